// Round 2
// baseline (20108.170 us; speedup 1.0000x reference)
//
#include <hip/hip_runtime.h>
#include <hip/hip_bf16.h>
#include <math.h>

#define L_IN 1549
#define S_OUT 512

typedef __hip_bfloat16 bf16;

// ---------- vector load/store helpers (8 contiguous elements, fp32 compute) ----
__device__ __forceinline__ void load8(const float* p, float v[8]) {
    float4 a = *(const float4*)p;
    float4 b = *(const float4*)(p + 4);
    v[0] = a.x; v[1] = a.y; v[2] = a.z; v[3] = a.w;
    v[4] = b.x; v[5] = b.y; v[6] = b.z; v[7] = b.w;
}
__device__ __forceinline__ void load8(const bf16* p, float v[8]) {
    float4 raw = *(const float4*)p;          // 8 bf16 in 16B
    const bf16* h = (const bf16*)&raw;
    #pragma unroll
    for (int i = 0; i < 8; ++i) v[i] = __bfloat162float(h[i]);
}
__device__ __forceinline__ void store8(float* p, const float v[8]) {
    float4 a, b;
    a.x = v[0]; a.y = v[1]; a.z = v[2]; a.w = v[3];
    b.x = v[4]; b.y = v[5]; b.z = v[6]; b.w = v[7];
    *(float4*)p = a;
    *(float4*)(p + 4) = b;
}
__device__ __forceinline__ void store8(bf16* p, const float v[8]) {
    union { float4 f; bf16 h[8]; } u;
    #pragma unroll
    for (int i = 0; i < 8; ++i) u.h[i] = __float2bfloat16(v[i]);
    *(float4*)p = u.f;
}

// ---------------------------------------------------------------------------
// conv1d(k=16,pad=1) + BN + ReLU + maxpool(3,3) + transpose -> h0 (B,512,32)
// ---------------------------------------------------------------------------
__global__ __launch_bounds__(256) void conv_bn_pool(
    const float* __restrict__ x, const float* __restrict__ w,
    const float* __restrict__ cb, const float* __restrict__ gamma,
    const float* __restrict__ beta, const float* __restrict__ mean,
    const float* __restrict__ var, float* __restrict__ h0)
{
    int b  = blockIdx.y;   // batch
    int sg = blockIdx.x;   // group of 8 pooled outputs
    __shared__ float xs[32][40];
    int tid = threadIdx.x;
    int base = sg * 24;    // x-index of first needed sample is base-1
    for (int i = tid; i < 32 * 40; i += 256) {
        int ci = i / 40, dl = i % 40;
        int l = base - 1 + dl;
        xs[ci][dl] = (l >= 0 && l < L_IN) ? x[(size_t)(b * 32 + ci) * L_IN + l] : 0.f;
    }
    __syncthreads();
    int c = tid & 31, sl = tid >> 5;  // c_out, local s
    float scale = gamma[c] * rsqrtf(var[c] + 1e-5f);
    float shift = beta[c] - mean[c] * scale;
    float bias = cb[c];
    float best = -1e30f;
    #pragma unroll
    for (int p = 0; p < 3; ++p) {
        float acc = bias;
        for (int ci = 0; ci < 32; ++ci) {
            const float* wr = w + (size_t)(c * 32 + ci) * 16;
            int off = 3 * sl + p;
            #pragma unroll
            for (int kk = 0; kk < 16; ++kk) acc += xs[ci][off + kk] * wr[kk];
        }
        float y = acc * scale + shift;
        y = fmaxf(y, 0.f);
        best = fmaxf(best, y);
    }
    int s = sg * 8 + sl;
    h0[((size_t)b * S_OUT + s) * 32 + c] = best;
}

// ---------------------------------------------------------------------------
// W_hh (1024,256) -> Wt (256,1024):  Wt[k*1024+g] = W[g*256+k]
// ---------------------------------------------------------------------------
__global__ void transpose_whh(const float* __restrict__ W, float* __restrict__ Wt)
{
    int i = blockIdx.x * 256 + threadIdx.x;   // 262144 total
    int g = i >> 8;
    int k = i & 255;
    Wt[(size_t)k * 1024 + g] = W[(size_t)g * 256 + k];
}

// ---------------------------------------------------------------------------
// C = A @ B^T + bias.  A (M,K), B (N,K) fp32 weights. 128x128 tile, BK=16,
// 8x8/thread, fp32 accumulate. TA/TC select storage dtype of A/C.
// grid.z selects among up to 3 (B,bias,C) sets sharing A.
// ---------------------------------------------------------------------------
template <typename TA, typename TC>
__global__ __launch_bounds__(256) void gemm128(
    const TA* __restrict__ A,
    const float* __restrict__ Bm0, const float* __restrict__ Bm1, const float* __restrict__ Bm2,
    const float* __restrict__ bs0, const float* __restrict__ bs1, const float* __restrict__ bs2,
    TC* __restrict__ Cm0, TC* __restrict__ Cm1, TC* __restrict__ Cm2,
    int M, int N, int K)
{
    int z = blockIdx.z;
    const float* B = (z == 0) ? Bm0 : ((z == 1) ? Bm1 : Bm2);
    const float* bias = (z == 0) ? bs0 : ((z == 1) ? bs1 : bs2);
    TC* C = (z == 0) ? Cm0 : ((z == 1) ? Cm1 : Cm2);

    __shared__ float As[16][136];
    __shared__ float Bs[16][136];

    int tid = threadIdx.x;
    int bn = blockIdx.x, bm = blockIdx.y;
    int tm = (tid >> 4) << 3;
    int tn = (tid & 15) << 3;

    int lr = tid >> 1;             // 0..127
    int lc = (tid & 1) << 3;       // 0 or 8

    const TA* Ap = A + (size_t)(bm * 128 + lr) * K + lc;
    const float* Bp = B + (size_t)(bn * 128 + lr) * K + lc;

    float acc[8][8];
    #pragma unroll
    for (int i = 0; i < 8; ++i)
        #pragma unroll
        for (int j = 0; j < 8; ++j) acc[i][j] = 0.f;

    for (int k0 = 0; k0 < K; k0 += 16) {
        float av[8], bv[8];
        load8(Ap + k0, av);
        load8(Bp + k0, bv);
        __syncthreads();
        #pragma unroll
        for (int q = 0; q < 8; ++q) {
            As[lc + q][lr] = av[q];
            Bs[lc + q][lr] = bv[q];
        }
        __syncthreads();
        #pragma unroll
        for (int kk = 0; kk < 16; ++kk) {
            float4 av0 = *(const float4*)&As[kk][tm];
            float4 av1 = *(const float4*)&As[kk][tm + 4];
            float4 bv0 = *(const float4*)&Bs[kk][tn];
            float4 bv1 = *(const float4*)&Bs[kk][tn + 4];
            float a_[8] = {av0.x, av0.y, av0.z, av0.w, av1.x, av1.y, av1.z, av1.w};
            float b_[8] = {bv0.x, bv0.y, bv0.z, bv0.w, bv1.x, bv1.y, bv1.z, bv1.w};
            #pragma unroll
            for (int i = 0; i < 8; ++i)
                #pragma unroll
                for (int j = 0; j < 8; ++j)
                    acc[i][j] += a_[i] * b_[j];
        }
    }
    float bias_r[8];
    #pragma unroll
    for (int j = 0; j < 8; ++j) bias_r[j] = bias[bn * 128 + tn + j];
    #pragma unroll
    for (int i = 0; i < 8; ++i) {
        float o[8];
        #pragma unroll
        for (int j = 0; j < 8; ++j) o[j] = acc[i][j] + bias_r[j];
        store8(C + (size_t)(bm * 128 + tm + i) * N + bn * 128 + tn, o);
    }
}

// ---------------------------------------------------------------------------
// Bidirectional LSTM recurrence. One block per (batch, dir); 512 threads.
// xg holds x@W_ih^T + b precomputed, stored bf16 (B,S,1024). h in LDS fp32,
// c in registers. Wt fp32 (256,1024) streamed from L2.
// ---------------------------------------------------------------------------
__global__ __launch_bounds__(512) void lstm_dual(
    const bf16* __restrict__ xg_f, const bf16* __restrict__ xg_b,
    const float* __restrict__ Wt_f, const float* __restrict__ Wt_b,
    bf16* __restrict__ out)
{
    int bid = blockIdx.x;
    int b = bid & 63;
    int dir = bid >> 6;
    const bf16* xg = dir ? xg_b : xg_f;
    const float2* Wt2 = (const float2*)(dir ? Wt_b : Wt_f);
    int col0 = dir ? 256 : 0;
    int t = threadIdx.x;  // 0..511

    __shared__ float hprev[256];
    __shared__ float gates[1024];

    if (t < 256) hprev[t] = 0.f;
    float cst = 0.f;
    __syncthreads();

    for (int step = 0; step < 512; ++step) {
        int ts = dir ? (511 - step) : step;
        const __hip_bfloat162* xg2 =
            (const __hip_bfloat162*)(xg + ((size_t)b * 512 + ts) * 1024);
        __hip_bfloat162 xv = xg2[t];
        float2 acc;
        acc.x = __bfloat162float(xv.x);
        acc.y = __bfloat162float(xv.y);
        #pragma unroll 8
        for (int k = 0; k < 256; ++k) {
            float hk = hprev[k];
            float2 wv = Wt2[(size_t)k * 512 + t];
            acc.x += wv.x * hk;
            acc.y += wv.y * hk;
        }
        ((float2*)gates)[t] = acc;
        __syncthreads();
        if (t < 256) {
            float gi = gates[t], gf = gates[256 + t], gg = gates[512 + t], go = gates[768 + t];
            float si = 1.f / (1.f + expf(-gi));
            float sf = 1.f / (1.f + expf(-gf));
            float so = 1.f / (1.f + expf(-go));
            cst = sf * cst + si * tanhf(gg);
            float h = so * tanhf(cst);
            hprev[t] = h;
            out[((size_t)b * 512 + ts) * 512 + col0 + t] = __float2bfloat16(h);
        }
        __syncthreads();
    }
}

// ---------------------------------------------------------------------------
// Fused attention: scores (q.k/8), log_softmax over the 8 HEADS (axis=1),
// ctx = sum_t la*v, r = o1 + ctx (in-place over o1: each element read exactly
// once by the thread that writes it).  Block = (b, 8 s-rows); chunks of 8 t.
// ---------------------------------------------------------------------------
__global__ __launch_bounds__(256) void attention(
    const bf16* __restrict__ q, const bf16* __restrict__ k, const bf16* __restrict__ v,
    const bf16* o1, bf16* r)
{
    __shared__ float qs[8 * 520];
    __shared__ float ks[8 * 520];
    __shared__ float vs[8 * 520];
    __shared__ float la[8 * 8 * 8];  // [s][t][h]
    int b = blockIdx.y;
    int s0 = blockIdx.x * 8;
    int tid = threadIdx.x;

    for (int i = tid; i < 8 * 64; i += 256) {
        int row = i >> 6, c8 = (i & 63) << 3;
        float v8[8];
        load8(q + ((size_t)(b * 512 + s0 + row)) * 512 + c8, v8);
        #pragma unroll
        for (int j = 0; j < 8; ++j) qs[row * 520 + c8 + j] = v8[j];
    }

    int ss = tid >> 5;          // 0..7 (score s, also ctx s)
    int tt = (tid >> 2) & 7;    // 0..7 (score t)
    int hh = tid & 3;           // 0..3 (2 heads each)
    int nb = tid & 31;          // ctx channel base

    float ctx[16];
    #pragma unroll
    for (int j = 0; j < 16; ++j) ctx[j] = 0.f;

    for (int tc = 0; tc < 512; tc += 8) {
        __syncthreads();
        for (int i = tid; i < 8 * 64; i += 256) {
            int row = i >> 6, c8 = (i & 63) << 3;
            size_t g = ((size_t)(b * 512 + tc + row)) * 512 + c8;
            float k8[8], v8[8];
            load8(k + g, k8);
            load8(v + g, v8);
            #pragma unroll
            for (int j = 0; j < 8; ++j) {
                ks[row * 520 + c8 + j] = k8[j];
                vs[row * 520 + c8 + j] = v8[j];
            }
        }
        __syncthreads();
        // scores for (ss, tt), heads {hh, hh+4}
        float sc[2];
        #pragma unroll
        for (int u = 0; u < 2; ++u) {
            int h = hh + u * 4;
            const float4* qp = (const float4*)&qs[ss * 520 + h * 64];
            const float4* kp = (const float4*)&ks[tt * 520 + h * 64];
            float a = 0.f;
            #pragma unroll
            for (int d4 = 0; d4 < 16; ++d4) {
                float4 qv = qp[d4], kv = kp[d4];
                a += qv.x * kv.x + qv.y * kv.y + qv.z * kv.z + qv.w * kv.w;
            }
            sc[u] = a * 0.125f;
        }
        float m = fmaxf(sc[0], sc[1]);
        m = fmaxf(m, __shfl_xor(m, 1));
        m = fmaxf(m, __shfl_xor(m, 2));
        float sum = expf(sc[0] - m) + expf(sc[1] - m);
        sum += __shfl_xor(sum, 1);
        sum += __shfl_xor(sum, 2);
        float lse = m + logf(sum);
        la[(ss * 8 + tt) * 8 + hh]     = sc[0] - lse;
        la[(ss * 8 + tt) * 8 + hh + 4] = sc[1] - lse;
        __syncthreads();
        // ctx accumulate: thread covers (s=ss, n = nb + 32j)
        #pragma unroll
        for (int t8 = 0; t8 < 8; ++t8) {
            float lav[8];
            #pragma unroll
            for (int h = 0; h < 8; ++h) lav[h] = la[(ss * 8 + t8) * 8 + h];
            #pragma unroll
            for (int j = 0; j < 16; ++j) {
                int n = nb + (j << 5);
                ctx[j] += lav[j >> 1] * vs[t8 * 520 + n];
            }
        }
    }
    size_t base = ((size_t)(b * 512 + s0 + ss)) * 512;
    #pragma unroll
    for (int j = 0; j < 16; ++j) {
        int n = nb + (j << 5);
        float o = __bfloat162float(o1[base + n]);
        r[base + n] = __float2bfloat16(o + ctx[j]);
    }
}

// ---------------------------------------------------------------------------
// LayerNorm(last dim) -> mean over S -> fc.  One block per (b, s) row.
// ---------------------------------------------------------------------------
__device__ __forceinline__ float block_sum(float val, float* red, int tid)
{
    #pragma unroll
    for (int o = 32; o > 0; o >>= 1) val += __shfl_down(val, o);
    __syncthreads();
    if ((tid & 63) == 0) red[tid >> 6] = val;
    __syncthreads();
    return red[0] + red[1] + red[2] + red[3];
}

__global__ __launch_bounds__(256) void ln_pool_fc(
    const bf16* __restrict__ r, const float* __restrict__ g, const float* __restrict__ bt,
    const float* __restrict__ fcw, const float* __restrict__ fcb, float* __restrict__ out)
{
    __shared__ float red[4];
    int b = blockIdx.y, s = blockIdx.x, tid = threadIdx.x;
    const bf16* row = r + ((size_t)(b * 512 + s)) * 512;
    __hip_bfloat162 rv = *(const __hip_bfloat162*)(row + tid * 2);
    float v0 = __bfloat162float(rv.x), v1 = __bfloat162float(rv.y);
    float tot = block_sum(v0 + v1, red, tid);
    float mu = tot * (1.f / 512.f);
    float d0 = v0 - mu, d1 = v1 - mu;
    float sq = block_sum(d0 * d0 + d1 * d1, red, tid);
    float rs = rsqrtf(sq * (1.f / 512.f) + 1e-5f);
    int n0 = tid * 2;
    float term = d0 * rs * g[n0] * fcw[n0] + d1 * rs * g[n0 + 1] * fcw[n0 + 1];
    if (s == 0) term += 512.f * (bt[n0] * fcw[n0] + bt[n0 + 1] * fcw[n0 + 1]);
    float D = block_sum(term, red, tid);
    if (tid == 0) {
        float val = D * (1.f / 512.f);
        if (s == 0) val += fcb[0];
        atomicAdd(out + b, val);
    }
}

// ---------------------------------------------------------------------------
// Workspace layout (200 MiB total):
//   [0,128MiB)      xg fwd/bwd bf16 (2 x 33,554,432 elts) -> reused as q,k,v
//   [128,160MiB)    out0 bf16 (16,777,216 elts)
//   [160,192MiB)    out1 bf16 (attention writes r in-place here)
//   [192,196MiB)    h0 fp32 (1,048,576 elts)
//   [196,200MiB)    Wt x4 fp32 (4 x 262,144 elts)
// ---------------------------------------------------------------------------
extern "C" void kernel_launch(void* const* d_in, const int* in_sizes, int n_in,
                              void* d_out, int out_size, void* d_ws, size_t ws_size,
                              hipStream_t stream)
{
    (void)in_sizes; (void)n_in; (void)ws_size;
    const float* x      = (const float*)d_in[0];
    const float* conv_w = (const float*)d_in[1];
    const float* conv_b = (const float*)d_in[2];
    const float* bn_g   = (const float*)d_in[3];
    const float* bn_b   = (const float*)d_in[4];
    const float* bn_m   = (const float*)d_in[5];
    const float* bn_v   = (const float*)d_in[6];
    const float* W_ih0f = (const float*)d_in[7];
    const float* W_hh0f = (const float*)d_in[8];
    const float* b0f    = (const float*)d_in[9];
    const float* W_ih0b = (const float*)d_in[10];
    const float* W_hh0b = (const float*)d_in[11];
    const float* b0b    = (const float*)d_in[12];
    const float* W_ih1f = (const float*)d_in[13];
    const float* W_hh1f = (const float*)d_in[14];
    const float* b1f    = (const float*)d_in[15];
    const float* W_ih1b = (const float*)d_in[16];
    const float* W_hh1b = (const float*)d_in[17];
    const float* b1b    = (const float*)d_in[18];
    const float* Wq = (const float*)d_in[19];
    const float* bq = (const float*)d_in[20];
    const float* Wk = (const float*)d_in[21];
    const float* bk = (const float*)d_in[22];
    const float* Wv = (const float*)d_in[23];
    const float* bv = (const float*)d_in[24];
    const float* ln_g = (const float*)d_in[25];
    const float* ln_b = (const float*)d_in[26];
    const float* fc_w = (const float*)d_in[27];
    const float* fc_b = (const float*)d_in[28];
    float* out = (float*)d_out;

    char* ws = (char*)d_ws;
    bf16* xgf  = (bf16*)ws;                               // 33,554,432 elts
    bf16* xgb  = xgf + 33554432;                          // 33,554,432 elts
    bf16* out0 = (bf16*)(ws + 134217728);                 // 16,777,216 elts
    bf16* out1 = (bf16*)(ws + 167772160);                 // 16,777,216 elts
    float* h0   = (float*)(ws + 201326592);               // 1,048,576 elts
    float* wt0f = (float*)(ws + 205520896);               // 262,144 elts each
    float* wt0b = wt0f + 262144;
    float* wt1f = wt0b + 262144;
    float* wt1b = wt1f + 262144;
    // q,k,v alias the (dead after lstm1) xg region
    bf16* qb = xgf;
    bf16* kb = xgf + 16777216;
    bf16* vb = xgb;

    hipMemsetAsync(d_out, 0, (size_t)out_size * sizeof(float), stream);

    transpose_whh<<<1024, 256, 0, stream>>>(W_hh0f, wt0f);
    transpose_whh<<<1024, 256, 0, stream>>>(W_hh0b, wt0b);
    transpose_whh<<<1024, 256, 0, stream>>>(W_hh1f, wt1f);
    transpose_whh<<<1024, 256, 0, stream>>>(W_hh1b, wt1b);

    conv_bn_pool<<<dim3(64, 64), 256, 0, stream>>>(
        x, conv_w, conv_b, bn_g, bn_b, bn_m, bn_v, h0);

    // layer-0 input projections (K=32), fwd+bwd in one launch
    gemm128<float, bf16><<<dim3(8, 256, 2), 256, 0, stream>>>(
        h0, W_ih0f, W_ih0b, nullptr, b0f, b0b, nullptr, xgf, xgb, nullptr,
        32768, 1024, 32);

    lstm_dual<<<128, 512, 0, stream>>>(xgf, xgb, wt0f, wt0b, out0);

    // layer-1 input projections (K=512)
    gemm128<bf16, bf16><<<dim3(8, 256, 2), 256, 0, stream>>>(
        out0, W_ih1f, W_ih1b, nullptr, b1f, b1b, nullptr, xgf, xgb, nullptr,
        32768, 1024, 512);

    lstm_dual<<<128, 512, 0, stream>>>(xgf, xgb, wt1f, wt1b, out1);

    // QKV projections (N=512), 3-way
    gemm128<bf16, bf16><<<dim3(4, 256, 3), 256, 0, stream>>>(
        out1, Wq, Wk, Wv, bq, bk, bv, qb, kb, vb,
        32768, 512, 512);

    attention<<<dim3(64, 64), 256, 0, stream>>>(qb, kb, vb, out1, out1);

    ln_pool_fc<<<dim3(512, 64), 256, 0, stream>>>(out1, ln_g, ln_b, fc_w, fc_b, out);
}

// Round 3
// 10098.947 us; speedup vs baseline: 1.9911x; 1.9911x over previous
//
#include <hip/hip_runtime.h>
#include <hip/hip_bf16.h>
#include <math.h>

#define L_IN 1549
#define S_OUT 512

typedef __hip_bfloat16 bf16;

__device__ __forceinline__ float bfbits2f(unsigned short u) {
    union { unsigned int i; float f; } x;
    x.i = ((unsigned int)u) << 16;
    return x.f;
}

// ---------- vector load/store helpers (8 contiguous elements, fp32 compute) ----
__device__ __forceinline__ void load8(const float* p, float v[8]) {
    float4 a = *(const float4*)p;
    float4 b = *(const float4*)(p + 4);
    v[0] = a.x; v[1] = a.y; v[2] = a.z; v[3] = a.w;
    v[4] = b.x; v[5] = b.y; v[6] = b.z; v[7] = b.w;
}
__device__ __forceinline__ void load8(const bf16* p, float v[8]) {
    float4 raw = *(const float4*)p;          // 8 bf16 in 16B
    const bf16* h = (const bf16*)&raw;
    #pragma unroll
    for (int i = 0; i < 8; ++i) v[i] = __bfloat162float(h[i]);
}
__device__ __forceinline__ void store8(float* p, const float v[8]) {
    float4 a, b;
    a.x = v[0]; a.y = v[1]; a.z = v[2]; a.w = v[3];
    b.x = v[4]; b.y = v[5]; b.z = v[6]; b.w = v[7];
    *(float4*)p = a;
    *(float4*)(p + 4) = b;
}
__device__ __forceinline__ void store8(bf16* p, const float v[8]) {
    union { float4 f; bf16 h[8]; } u;
    #pragma unroll
    for (int i = 0; i < 8; ++i) u.h[i] = __float2bfloat16(v[i]);
    *(float4*)p = u.f;
}

// ---------------------------------------------------------------------------
// conv1d(k=16,pad=1) + BN + ReLU + maxpool(3,3) + transpose -> h0 (B,512,32)
// ---------------------------------------------------------------------------
__global__ __launch_bounds__(256) void conv_bn_pool(
    const float* __restrict__ x, const float* __restrict__ w,
    const float* __restrict__ cb, const float* __restrict__ gamma,
    const float* __restrict__ beta, const float* __restrict__ mean,
    const float* __restrict__ var, float* __restrict__ h0)
{
    int b  = blockIdx.y;   // batch
    int sg = blockIdx.x;   // group of 8 pooled outputs
    __shared__ float xs[32][40];
    int tid = threadIdx.x;
    int base = sg * 24;    // x-index of first needed sample is base-1
    for (int i = tid; i < 32 * 40; i += 256) {
        int ci = i / 40, dl = i % 40;
        int l = base - 1 + dl;
        xs[ci][dl] = (l >= 0 && l < L_IN) ? x[(size_t)(b * 32 + ci) * L_IN + l] : 0.f;
    }
    __syncthreads();
    int c = tid & 31, sl = tid >> 5;  // c_out, local s
    float scale = gamma[c] * rsqrtf(var[c] + 1e-5f);
    float shift = beta[c] - mean[c] * scale;
    float bias = cb[c];
    float best = -1e30f;
    #pragma unroll
    for (int p = 0; p < 3; ++p) {
        float acc = bias;
        for (int ci = 0; ci < 32; ++ci) {
            const float* wr = w + (size_t)(c * 32 + ci) * 16;
            int off = 3 * sl + p;
            #pragma unroll
            for (int kk = 0; kk < 16; ++kk) acc += xs[ci][off + kk] * wr[kk];
        }
        float y = acc * scale + shift;
        y = fmaxf(y, 0.f);
        best = fmaxf(best, y);
    }
    int s = sg * 8 + sl;
    h0[((size_t)b * S_OUT + s) * 32 + c] = best;
}

// ---------------------------------------------------------------------------
// Pack W_hh (1024,256) fp32 -> bf16 layout Wp[k4][c][u], u = (k&3)*2 + (g&1),
// c = g>>1, k4 = k>>2.  Each float4 of Wp = 4 k-steps x 2 adjacent gate cols.
// ---------------------------------------------------------------------------
__global__ void pack_whh(const float* __restrict__ W, bf16* __restrict__ Wp)
{
    int i = blockIdx.x * 256 + threadIdx.x;   // 262144 total
    int u  = i & 7;
    int c  = (i >> 3) & 511;
    int k4 = i >> 12;
    int g = 2 * c + (u & 1);
    int k = 4 * k4 + (u >> 1);
    Wp[i] = __float2bfloat16(W[(size_t)g * 256 + k]);
}

// ---------------------------------------------------------------------------
// C = A @ B^T + bias.  A (M,K), B (N,K) fp32 weights. 128x128 tile, BK=16,
// 8x8/thread, fp32 accumulate. TA/TC select storage dtype of A/C.
// grid.z selects among up to 3 (B,bias,C) sets sharing A.
// ---------------------------------------------------------------------------
template <typename TA, typename TC>
__global__ __launch_bounds__(256) void gemm128(
    const TA* __restrict__ A,
    const float* __restrict__ Bm0, const float* __restrict__ Bm1, const float* __restrict__ Bm2,
    const float* __restrict__ bs0, const float* __restrict__ bs1, const float* __restrict__ bs2,
    TC* __restrict__ Cm0, TC* __restrict__ Cm1, TC* __restrict__ Cm2,
    int M, int N, int K)
{
    int z = blockIdx.z;
    const float* B = (z == 0) ? Bm0 : ((z == 1) ? Bm1 : Bm2);
    const float* bias = (z == 0) ? bs0 : ((z == 1) ? bs1 : bs2);
    TC* C = (z == 0) ? Cm0 : ((z == 1) ? Cm1 : Cm2);

    __shared__ float As[16][136];
    __shared__ float Bs[16][136];

    int tid = threadIdx.x;
    int bn = blockIdx.x, bm = blockIdx.y;
    int tm = (tid >> 4) << 3;
    int tn = (tid & 15) << 3;

    int lr = tid >> 1;             // 0..127
    int lc = (tid & 1) << 3;       // 0 or 8

    const TA* Ap = A + (size_t)(bm * 128 + lr) * K + lc;
    const float* Bp = B + (size_t)(bn * 128 + lr) * K + lc;

    float acc[8][8];
    #pragma unroll
    for (int i = 0; i < 8; ++i)
        #pragma unroll
        for (int j = 0; j < 8; ++j) acc[i][j] = 0.f;

    for (int k0 = 0; k0 < K; k0 += 16) {
        float av[8], bv[8];
        load8(Ap + k0, av);
        load8(Bp + k0, bv);
        __syncthreads();
        #pragma unroll
        for (int q = 0; q < 8; ++q) {
            As[lc + q][lr] = av[q];
            Bs[lc + q][lr] = bv[q];
        }
        __syncthreads();
        #pragma unroll
        for (int kk = 0; kk < 16; ++kk) {
            float4 av0 = *(const float4*)&As[kk][tm];
            float4 av1 = *(const float4*)&As[kk][tm + 4];
            float4 bv0 = *(const float4*)&Bs[kk][tn];
            float4 bv1 = *(const float4*)&Bs[kk][tn + 4];
            float a_[8] = {av0.x, av0.y, av0.z, av0.w, av1.x, av1.y, av1.z, av1.w};
            float b_[8] = {bv0.x, bv0.y, bv0.z, bv0.w, bv1.x, bv1.y, bv1.z, bv1.w};
            #pragma unroll
            for (int i = 0; i < 8; ++i)
                #pragma unroll
                for (int j = 0; j < 8; ++j)
                    acc[i][j] += a_[i] * b_[j];
        }
    }
    float bias_r[8];
    #pragma unroll
    for (int j = 0; j < 8; ++j) bias_r[j] = bias[bn * 128 + tn + j];
    #pragma unroll
    for (int i = 0; i < 8; ++i) {
        float o[8];
        #pragma unroll
        for (int j = 0; j < 8; ++j) o[j] = acc[i][j] + bias_r[j];
        store8(C + (size_t)(bm * 128 + tm + i) * N + bn * 128 + tn, o);
    }
}

// ---------------------------------------------------------------------------
// Bidirectional LSTM recurrence, v2. One block per (batch, dir); 1024 threads.
// K-split x2: threads [0,512) reduce k in [0,128), threads [512,1024) reduce
// k in [128,256); partials combined through LDS.  Each thread owns a column
// pair (2c, 2c+1); weights are bf16, packed so one float4 = 4k x 2cols,
// coalesced across c.  hprev is a wave-uniform (broadcast) ds_read_b128.
// ---------------------------------------------------------------------------
__global__ __launch_bounds__(1024) void lstm_dual(
    const bf16* __restrict__ xg_f, const bf16* __restrict__ xg_b,
    const bf16* __restrict__ Wp_f, const bf16* __restrict__ Wp_b,
    bf16* __restrict__ out)
{
    int bid = blockIdx.x;
    int b = bid & 63;
    int dir = bid >> 6;
    const bf16* xg = dir ? xg_b : xg_f;
    const float4* Wq = (const float4*)(dir ? Wp_b : Wp_f);  // [64][512] float4s
    int col0 = dir ? 256 : 0;
    int t = threadIdx.x;     // 0..1023
    int c = t & 511;         // column pair: gate cols (2c, 2c+1)
    int kh = t >> 9;         // K half

    __shared__ __align__(16) float hprev[256];
    __shared__ float2 partial[1024];
    __shared__ float gates[1024];

    if (t < 256) hprev[t] = 0.f;
    float cst = 0.f;
    __syncthreads();

    const float4* Wbase = Wq + (size_t)(kh * 32) * 512 + c;

    for (int step = 0; step < 512; ++step) {
        int ts = dir ? (511 - step) : step;
        // xg for the combine phase: issue early so it's in flight during matvec
        __hip_bfloat162 xv;
        if (t < 512)
            xv = ((const __hip_bfloat162*)(xg + ((size_t)b * 512 + ts) * 1024))[t];

        float accx = 0.f, accy = 0.f;
        #pragma unroll 8
        for (int k4 = 0; k4 < 32; ++k4) {
            union { float4 f; unsigned short u[8]; } w;
            w.f = Wbase[(size_t)k4 * 512];
            float4 hv = *(const float4*)&hprev[(kh * 32 + k4) * 4];
            accx += bfbits2f(w.u[0]) * hv.x + bfbits2f(w.u[2]) * hv.y
                  + bfbits2f(w.u[4]) * hv.z + bfbits2f(w.u[6]) * hv.w;
            accy += bfbits2f(w.u[1]) * hv.x + bfbits2f(w.u[3]) * hv.y
                  + bfbits2f(w.u[5]) * hv.z + bfbits2f(w.u[7]) * hv.w;
        }
        partial[t].x = accx;
        partial[t].y = accy;
        __syncthreads();

        if (t < 512) {
            float2 p0 = partial[t], p1 = partial[t + 512];
            float g0 = p0.x + p1.x + __bfloat162float(xv.x);
            float g1 = p0.y + p1.y + __bfloat162float(xv.y);
            *(float2*)&gates[2 * t] = make_float2(g0, g1);
        }
        __syncthreads();

        if (t < 256) {
            float gi = gates[t], gf = gates[256 + t], gg = gates[512 + t], go = gates[768 + t];
            float si = 1.f / (1.f + expf(-gi));
            float sf = 1.f / (1.f + expf(-gf));
            float so = 1.f / (1.f + expf(-go));
            cst = sf * cst + si * tanhf(gg);
            float h = so * tanhf(cst);
            hprev[t] = h;
            out[((size_t)b * 512 + ts) * 512 + col0 + t] = __float2bfloat16(h);
        }
        __syncthreads();
    }
}

// ---------------------------------------------------------------------------
// Fused attention: scores (q.k/8), log_softmax over the 8 HEADS (axis=1),
// ctx = sum_t la*v, r = o1 + ctx (in-place over o1: each element read exactly
// once by the thread that writes it).  Block = (b, 8 s-rows); chunks of 8 t.
// ---------------------------------------------------------------------------
__global__ __launch_bounds__(256) void attention(
    const bf16* __restrict__ q, const bf16* __restrict__ k, const bf16* __restrict__ v,
    const bf16* o1, bf16* r)
{
    __shared__ float qs[8 * 520];
    __shared__ float ks[8 * 520];
    __shared__ float vs[8 * 520];
    __shared__ float la[8 * 8 * 8];  // [s][t][h]
    int b = blockIdx.y;
    int s0 = blockIdx.x * 8;
    int tid = threadIdx.x;

    for (int i = tid; i < 8 * 64; i += 256) {
        int row = i >> 6, c8 = (i & 63) << 3;
        float v8[8];
        load8(q + ((size_t)(b * 512 + s0 + row)) * 512 + c8, v8);
        #pragma unroll
        for (int j = 0; j < 8; ++j) qs[row * 520 + c8 + j] = v8[j];
    }

    int ss = tid >> 5;          // 0..7 (score s, also ctx s)
    int tt = (tid >> 2) & 7;    // 0..7 (score t)
    int hh = tid & 3;           // 0..3 (2 heads each)
    int nb = tid & 31;          // ctx channel base

    float ctx[16];
    #pragma unroll
    for (int j = 0; j < 16; ++j) ctx[j] = 0.f;

    for (int tc = 0; tc < 512; tc += 8) {
        __syncthreads();
        for (int i = tid; i < 8 * 64; i += 256) {
            int row = i >> 6, c8 = (i & 63) << 3;
            size_t g = ((size_t)(b * 512 + tc + row)) * 512 + c8;
            float k8[8], v8[8];
            load8(k + g, k8);
            load8(v + g, v8);
            #pragma unroll
            for (int j = 0; j < 8; ++j) {
                ks[row * 520 + c8 + j] = k8[j];
                vs[row * 520 + c8 + j] = v8[j];
            }
        }
        __syncthreads();
        // scores for (ss, tt), heads {hh, hh+4}
        float sc[2];
        #pragma unroll
        for (int u = 0; u < 2; ++u) {
            int h = hh + u * 4;
            const float4* qp = (const float4*)&qs[ss * 520 + h * 64];
            const float4* kp = (const float4*)&ks[tt * 520 + h * 64];
            float a = 0.f;
            #pragma unroll
            for (int d4 = 0; d4 < 16; ++d4) {
                float4 qv = qp[d4], kv = kp[d4];
                a += qv.x * kv.x + qv.y * kv.y + qv.z * kv.z + qv.w * kv.w;
            }
            sc[u] = a * 0.125f;
        }
        float m = fmaxf(sc[0], sc[1]);
        m = fmaxf(m, __shfl_xor(m, 1));
        m = fmaxf(m, __shfl_xor(m, 2));
        float sum = expf(sc[0] - m) + expf(sc[1] - m);
        sum += __shfl_xor(sum, 1);
        sum += __shfl_xor(sum, 2);
        float lse = m + logf(sum);
        la[(ss * 8 + tt) * 8 + hh]     = sc[0] - lse;
        la[(ss * 8 + tt) * 8 + hh + 4] = sc[1] - lse;
        __syncthreads();
        // ctx accumulate: thread covers (s=ss, n = nb + 32j)
        #pragma unroll
        for (int t8 = 0; t8 < 8; ++t8) {
            float lav[8];
            #pragma unroll
            for (int h = 0; h < 8; ++h) lav[h] = la[(ss * 8 + t8) * 8 + h];
            #pragma unroll
            for (int j = 0; j < 16; ++j) {
                int n = nb + (j << 5);
                ctx[j] += lav[j >> 1] * vs[t8 * 520 + n];
            }
        }
    }
    size_t base = ((size_t)(b * 512 + s0 + ss)) * 512;
    #pragma unroll
    for (int j = 0; j < 16; ++j) {
        int n = nb + (j << 5);
        float o = __bfloat162float(o1[base + n]);
        r[base + n] = __float2bfloat16(o + ctx[j]);
    }
}

// ---------------------------------------------------------------------------
// LayerNorm(last dim) -> mean over S -> fc.  One block per (b, s) row.
// ---------------------------------------------------------------------------
__device__ __forceinline__ float block_sum(float val, float* red, int tid)
{
    #pragma unroll
    for (int o = 32; o > 0; o >>= 1) val += __shfl_down(val, o);
    __syncthreads();
    if ((tid & 63) == 0) red[tid >> 6] = val;
    __syncthreads();
    return red[0] + red[1] + red[2] + red[3];
}

__global__ __launch_bounds__(256) void ln_pool_fc(
    const bf16* __restrict__ r, const float* __restrict__ g, const float* __restrict__ bt,
    const float* __restrict__ fcw, const float* __restrict__ fcb, float* __restrict__ out)
{
    __shared__ float red[4];
    int b = blockIdx.y, s = blockIdx.x, tid = threadIdx.x;
    const bf16* row = r + ((size_t)(b * 512 + s)) * 512;
    __hip_bfloat162 rv = *(const __hip_bfloat162*)(row + tid * 2);
    float v0 = __bfloat162float(rv.x), v1 = __bfloat162float(rv.y);
    float tot = block_sum(v0 + v1, red, tid);
    float mu = tot * (1.f / 512.f);
    float d0 = v0 - mu, d1 = v1 - mu;
    float sq = block_sum(d0 * d0 + d1 * d1, red, tid);
    float rs = rsqrtf(sq * (1.f / 512.f) + 1e-5f);
    int n0 = tid * 2;
    float term = d0 * rs * g[n0] * fcw[n0] + d1 * rs * g[n0 + 1] * fcw[n0 + 1];
    if (s == 0) term += 512.f * (bt[n0] * fcw[n0] + bt[n0 + 1] * fcw[n0 + 1]);
    float D = block_sum(term, red, tid);
    if (tid == 0) {
        float val = D * (1.f / 512.f);
        if (s == 0) val += fcb[0];
        atomicAdd(out + b, val);
    }
}

// ---------------------------------------------------------------------------
// Workspace layout (<= 200 MiB total):
//   [0,128MiB)      xg fwd/bwd bf16 (2 x 33,554,432 elts) -> reused as q,k,v
//   [128,160MiB)    out0 bf16 (16,777,216 elts)
//   [160,192MiB)    out1 bf16 (attention writes r in-place here)
//   [192,196MiB)    h0 fp32 (1,048,576 elts)
//   [196,198MiB)    packed bf16 W_hh x4 (4 x 262,144 elts)
// ---------------------------------------------------------------------------
extern "C" void kernel_launch(void* const* d_in, const int* in_sizes, int n_in,
                              void* d_out, int out_size, void* d_ws, size_t ws_size,
                              hipStream_t stream)
{
    (void)in_sizes; (void)n_in; (void)ws_size;
    const float* x      = (const float*)d_in[0];
    const float* conv_w = (const float*)d_in[1];
    const float* conv_b = (const float*)d_in[2];
    const float* bn_g   = (const float*)d_in[3];
    const float* bn_b   = (const float*)d_in[4];
    const float* bn_m   = (const float*)d_in[5];
    const float* bn_v   = (const float*)d_in[6];
    const float* W_ih0f = (const float*)d_in[7];
    const float* W_hh0f = (const float*)d_in[8];
    const float* b0f    = (const float*)d_in[9];
    const float* W_ih0b = (const float*)d_in[10];
    const float* W_hh0b = (const float*)d_in[11];
    const float* b0b    = (const float*)d_in[12];
    const float* W_ih1f = (const float*)d_in[13];
    const float* W_hh1f = (const float*)d_in[14];
    const float* b1f    = (const float*)d_in[15];
    const float* W_ih1b = (const float*)d_in[16];
    const float* W_hh1b = (const float*)d_in[17];
    const float* b1b    = (const float*)d_in[18];
    const float* Wq = (const float*)d_in[19];
    const float* bq = (const float*)d_in[20];
    const float* Wk = (const float*)d_in[21];
    const float* bk = (const float*)d_in[22];
    const float* Wv = (const float*)d_in[23];
    const float* bv = (const float*)d_in[24];
    const float* ln_g = (const float*)d_in[25];
    const float* ln_b = (const float*)d_in[26];
    const float* fc_w = (const float*)d_in[27];
    const float* fc_b = (const float*)d_in[28];
    float* out = (float*)d_out;

    char* ws = (char*)d_ws;
    bf16* xgf  = (bf16*)ws;                               // 33,554,432 elts
    bf16* xgb  = xgf + 33554432;                          // 33,554,432 elts
    bf16* out0 = (bf16*)(ws + 134217728);                 // 16,777,216 elts
    bf16* out1 = (bf16*)(ws + 167772160);                 // 16,777,216 elts
    float* h0  = (float*)(ws + 201326592);                // 1,048,576 elts
    bf16* wp0f = (bf16*)(ws + 205520896);                 // 262,144 elts each
    bf16* wp0b = wp0f + 262144;
    bf16* wp1f = wp0b + 262144;
    bf16* wp1b = wp1f + 262144;
    // q,k,v alias the (dead after lstm1) xg region
    bf16* qb = xgf;
    bf16* kb = xgf + 16777216;
    bf16* vb = xgb;

    hipMemsetAsync(d_out, 0, (size_t)out_size * sizeof(float), stream);

    pack_whh<<<1024, 256, 0, stream>>>(W_hh0f, wp0f);
    pack_whh<<<1024, 256, 0, stream>>>(W_hh0b, wp0b);
    pack_whh<<<1024, 256, 0, stream>>>(W_hh1f, wp1f);
    pack_whh<<<1024, 256, 0, stream>>>(W_hh1b, wp1b);

    conv_bn_pool<<<dim3(64, 64), 256, 0, stream>>>(
        x, conv_w, conv_b, bn_g, bn_b, bn_m, bn_v, h0);

    // layer-0 input projections (K=32), fwd+bwd in one launch
    gemm128<float, bf16><<<dim3(8, 256, 2), 256, 0, stream>>>(
        h0, W_ih0f, W_ih0b, nullptr, b0f, b0b, nullptr, xgf, xgb, nullptr,
        32768, 1024, 32);

    lstm_dual<<<128, 1024, 0, stream>>>(xgf, xgb, wp0f, wp0b, out0);

    // layer-1 input projections (K=512)
    gemm128<bf16, bf16><<<dim3(8, 256, 2), 256, 0, stream>>>(
        out0, W_ih1f, W_ih1b, nullptr, b1f, b1b, nullptr, xgf, xgb, nullptr,
        32768, 1024, 512);

    lstm_dual<<<128, 1024, 0, stream>>>(xgf, xgb, wp1f, wp1b, out1);

    // QKV projections (N=512), 3-way
    gemm128<bf16, bf16><<<dim3(4, 256, 3), 256, 0, stream>>>(
        out1, Wq, Wk, Wv, bq, bk, bv, qb, kb, vb,
        32768, 512, 512);

    attention<<<dim3(64, 64), 256, 0, stream>>>(qb, kb, vb, out1, out1);

    ln_pool_fc<<<dim3(512, 64), 256, 0, stream>>>(out1, ln_g, ln_b, fc_w, fc_b, out);
}

// Round 4
// 8201.152 us; speedup vs baseline: 2.4519x; 1.2314x over previous
//
#include <hip/hip_runtime.h>
#include <hip/hip_bf16.h>
#include <math.h>

#define L_IN 1549
#define S_OUT 512

typedef __hip_bfloat16 bf16;
typedef __attribute__((ext_vector_type(8))) short bfrag;    // 8 bf16 (4 VGPRs)
typedef __attribute__((ext_vector_type(4))) float f32x4;    // MFMA accumulator

__device__ __forceinline__ float bfbits2f(unsigned short u) {
    union { unsigned int i; float f; } x;
    x.i = ((unsigned int)u) << 16;
    return x.f;
}
__device__ __forceinline__ float4 ld4bf(const bf16* p) {   // 4 bf16 (8B) -> float4
    union { uint2 u; unsigned short s[4]; } w;
    w.u = *(const uint2*)p;
    return make_float4(bfbits2f(w.s[0]), bfbits2f(w.s[1]), bfbits2f(w.s[2]), bfbits2f(w.s[3]));
}
__device__ __forceinline__ void load8(const bf16* p, float v[8]) {
    float4 raw = *(const float4*)p;
    const unsigned short* h = (const unsigned short*)&raw;
    #pragma unroll
    for (int i = 0; i < 8; ++i) v[i] = bfbits2f(h[i]);
}
__device__ __forceinline__ void store8(bf16* p, const float v[8]) {
    union { float4 f; unsigned short h[8]; } u;
    #pragma unroll
    for (int i = 0; i < 8; ++i) {
        union { float f; unsigned int i; } x; x.f = v[i];
        // round-to-nearest-even bf16
        unsigned int lsb = (x.i >> 16) & 1;
        u.h[i] = (unsigned short)((x.i + 0x7fff + lsb) >> 16);
    }
    *(float4*)p = u.f;
}

// ---------------------------------------------------------------------------
// conv1d(k=16,pad=1) + BN + ReLU + maxpool(3,3) + transpose -> h0 (B,512,32) bf16
// ---------------------------------------------------------------------------
__global__ __launch_bounds__(256) void conv_bn_pool(
    const float* __restrict__ x, const float* __restrict__ w,
    const float* __restrict__ cb, const float* __restrict__ gamma,
    const float* __restrict__ beta, const float* __restrict__ mean,
    const float* __restrict__ var, bf16* __restrict__ h0)
{
    int b  = blockIdx.y;
    int sg = blockIdx.x;
    __shared__ float xs[32][40];
    int tid = threadIdx.x;
    int base = sg * 24;
    for (int i = tid; i < 32 * 40; i += 256) {
        int ci = i / 40, dl = i % 40;
        int l = base - 1 + dl;
        xs[ci][dl] = (l >= 0 && l < L_IN) ? x[(size_t)(b * 32 + ci) * L_IN + l] : 0.f;
    }
    __syncthreads();
    int c = tid & 31, sl = tid >> 5;
    float scale = gamma[c] * rsqrtf(var[c] + 1e-5f);
    float shift = beta[c] - mean[c] * scale;
    float bias = cb[c];
    float best = -1e30f;
    #pragma unroll
    for (int p = 0; p < 3; ++p) {
        float acc = bias;
        for (int ci = 0; ci < 32; ++ci) {
            const float* wr = w + (size_t)(c * 32 + ci) * 16;
            int off = 3 * sl + p;
            #pragma unroll
            for (int kk = 0; kk < 16; ++kk) acc += xs[ci][off + kk] * wr[kk];
        }
        float y = acc * scale + shift;
        y = fmaxf(y, 0.f);
        best = fmaxf(best, y);
    }
    int s = sg * 8 + sl;
    h0[((size_t)b * S_OUT + s) * 32 + c] = __float2bfloat16(best);
}

// ---------------------------------------------------------------------------
// fp32 -> bf16 elementwise pack
// ---------------------------------------------------------------------------
__global__ void pack_bf16(const float* __restrict__ src, bf16* __restrict__ dst, int n)
{
    int i = blockIdx.x * 256 + threadIdx.x;
    if (i < n) dst[i] = __float2bfloat16(src[i]);
}

// ---------------------------------------------------------------------------
// Pack W_hh (1024,256) fp32 -> bf16 layout Wp[k4][c][u], u = (k&3)*2 + (g&1)
// ---------------------------------------------------------------------------
__global__ void pack_whh(const float* __restrict__ W, bf16* __restrict__ Wp)
{
    int i = blockIdx.x * 256 + threadIdx.x;   // 262144 total
    int u  = i & 7;
    int c  = (i >> 3) & 511;
    int k4 = i >> 12;
    int g = 2 * c + (u & 1);
    int k = 4 * k4 + (u >> 1);
    Wp[i] = __float2bfloat16(W[(size_t)g * 256 + k]);
}

// ---------------------------------------------------------------------------
// MFMA bf16 GEMM:  C = A @ B^T + bias.  A (M,K) bf16 rm, B (N,K) bf16 rm.
// 128x128 block tile, BK=32; 4 waves, each owning a 64x64 tile (4x4 MFMAs of
// 16x16x32).  grid.z selects among up to 3 (B,bias,C) sets sharing A.
// Fragment layouts (m89/m91-verified): A/B [idx=lane&15][k=(lane>>4)*8+j];
// C col=lane&15, row=(lane>>4)*4+reg.
// ---------------------------------------------------------------------------
__global__ __launch_bounds__(256) void gemm_mfma(
    const bf16* __restrict__ A,
    const bf16* __restrict__ Bm0, const bf16* __restrict__ Bm1, const bf16* __restrict__ Bm2,
    const float* __restrict__ bs0, const float* __restrict__ bs1, const float* __restrict__ bs2,
    bf16* __restrict__ Cm0, bf16* __restrict__ Cm1, bf16* __restrict__ Cm2,
    int M, int N, int K)
{
    int z = blockIdx.z;
    const bf16* B = (z == 0) ? Bm0 : ((z == 1) ? Bm1 : Bm2);
    const float* bias = (z == 0) ? bs0 : ((z == 1) ? bs1 : bs2);
    bf16* C = (z == 0) ? Cm0 : ((z == 1) ? Cm1 : Cm2);

    __shared__ bf16 As[128 * 32];
    __shared__ bf16 Bs[128 * 32];

    int tid = threadIdx.x;
    int lane = tid & 63;
    int wave = tid >> 6;
    int bm = blockIdx.y, bn = blockIdx.x;
    int wm = (wave >> 1) * 64;      // wave row offset in tile
    int wn = (wave & 1) * 64;       // wave col offset in tile

    // staging: thread covers rows sr and sr+64, 16B (8 bf16) each
    int sr = tid >> 2;
    int sc = (tid & 3) * 8;
    const bf16* Ag = A + (size_t)(bm * 128 + sr) * K + sc;
    const bf16* Bg = B + (size_t)(bn * 128 + sr) * K + sc;

    // fragment read offsets
    int fm = lane & 15;
    int fk = (lane >> 4) * 8;

    f32x4 acc[4][4];
    #pragma unroll
    for (int i = 0; i < 4; ++i)
        #pragma unroll
        for (int j = 0; j < 4; ++j) acc[i][j] = (f32x4)(0.f);

    for (int k0 = 0; k0 < K; k0 += 32) {
        float4 a0 = *(const float4*)(Ag + k0);
        float4 a1 = *(const float4*)(Ag + (size_t)64 * K + k0);
        float4 b0 = *(const float4*)(Bg + k0);
        float4 b1 = *(const float4*)(Bg + (size_t)64 * K + k0);
        __syncthreads();
        *(float4*)(As + sr * 32 + sc)        = a0;
        *(float4*)(As + (sr + 64) * 32 + sc) = a1;
        *(float4*)(Bs + sr * 32 + sc)        = b0;
        *(float4*)(Bs + (sr + 64) * 32 + sc) = b1;
        __syncthreads();

        bfrag af[4], bfr[4];
        #pragma unroll
        for (int i = 0; i < 4; ++i)
            af[i] = *(const bfrag*)(As + (wm + i * 16 + fm) * 32 + fk);
        #pragma unroll
        for (int j = 0; j < 4; ++j)
            bfr[j] = *(const bfrag*)(Bs + (wn + j * 16 + fm) * 32 + fk);
        #pragma unroll
        for (int i = 0; i < 4; ++i)
            #pragma unroll
            for (int j = 0; j < 4; ++j)
                acc[i][j] = __builtin_amdgcn_mfma_f32_16x16x32_bf16(
                    af[i], bfr[j], acc[i][j], 0, 0, 0);
    }

    int rbase = (lane >> 4) * 4;
    #pragma unroll
    for (int j = 0; j < 4; ++j) {
        int n = bn * 128 + wn + j * 16 + (lane & 15);
        float bv = bias[n];
        #pragma unroll
        for (int i = 0; i < 4; ++i) {
            #pragma unroll
            for (int r = 0; r < 4; ++r) {
                int m = bm * 128 + wm + i * 16 + rbase + r;
                C[(size_t)m * N + n] = __float2bfloat16(acc[i][j][r] + bv);
            }
        }
    }
}

// ---------------------------------------------------------------------------
// Bidirectional LSTM recurrence (unchanged from round 3).
// ---------------------------------------------------------------------------
__global__ __launch_bounds__(1024) void lstm_dual(
    const bf16* __restrict__ xg_f, const bf16* __restrict__ xg_b,
    const bf16* __restrict__ Wp_f, const bf16* __restrict__ Wp_b,
    bf16* __restrict__ out)
{
    int bid = blockIdx.x;
    int b = bid & 63;
    int dir = bid >> 6;
    const bf16* xg = dir ? xg_b : xg_f;
    const float4* Wq = (const float4*)(dir ? Wp_b : Wp_f);
    int col0 = dir ? 256 : 0;
    int t = threadIdx.x;
    int c = t & 511;
    int kh = t >> 9;

    __shared__ __align__(16) float hprev[256];
    __shared__ float2 partial[1024];
    __shared__ float gates[1024];

    if (t < 256) hprev[t] = 0.f;
    float cst = 0.f;
    __syncthreads();

    const float4* Wbase = Wq + (size_t)(kh * 32) * 512 + c;

    for (int step = 0; step < 512; ++step) {
        int ts = dir ? (511 - step) : step;
        __hip_bfloat162 xv;
        if (t < 512)
            xv = ((const __hip_bfloat162*)(xg + ((size_t)b * 512 + ts) * 1024))[t];

        float accx = 0.f, accy = 0.f;
        #pragma unroll 8
        for (int k4 = 0; k4 < 32; ++k4) {
            union { float4 f; unsigned short u[8]; } w;
            w.f = Wbase[(size_t)k4 * 512];
            float4 hv = *(const float4*)&hprev[(kh * 32 + k4) * 4];
            accx += bfbits2f(w.u[0]) * hv.x + bfbits2f(w.u[2]) * hv.y
                  + bfbits2f(w.u[4]) * hv.z + bfbits2f(w.u[6]) * hv.w;
            accy += bfbits2f(w.u[1]) * hv.x + bfbits2f(w.u[3]) * hv.y
                  + bfbits2f(w.u[5]) * hv.z + bfbits2f(w.u[7]) * hv.w;
        }
        partial[t].x = accx;
        partial[t].y = accy;
        __syncthreads();

        if (t < 512) {
            float2 p0 = partial[t], p1 = partial[t + 512];
            float g0 = p0.x + p1.x + __bfloat162float(xv.x);
            float g1 = p0.y + p1.y + __bfloat162float(xv.y);
            *(float2*)&gates[2 * t] = make_float2(g0, g1);
        }
        __syncthreads();

        if (t < 256) {
            float gi = gates[t], gf = gates[256 + t], gg = gates[512 + t], go = gates[768 + t];
            float si = 1.f / (1.f + expf(-gi));
            float sf = 1.f / (1.f + expf(-gf));
            float so = 1.f / (1.f + expf(-go));
            cst = sf * cst + si * tanhf(gg);
            float h = so * tanhf(cst);
            hprev[t] = h;
            out[((size_t)b * 512 + ts) * 512 + col0 + t] = __float2bfloat16(h);
        }
        __syncthreads();
    }
}

// ---------------------------------------------------------------------------
// Fused attention v2, bank-conflict-free.
//   scores: wave hh computes heads {hh,hh+4} for all (ss,tt); raw -> la LDS
//   log_softmax over heads: LDS pass (stride-9 rows)
//   ctx: per (cs,nb) accumulation, r = o1 + ctx in-place.
// Staging: split-half float4 writes (uniform 8 words/bank).
// ---------------------------------------------------------------------------
__global__ __launch_bounds__(256) void attention(
    const bf16* __restrict__ q, const bf16* __restrict__ k, const bf16* __restrict__ v,
    const bf16* o1, bf16* r)
{
    __shared__ float qs[8 * 520];
    __shared__ float ks[8 * 520];
    __shared__ float vs[8 * 520];
    __shared__ float la[64 * 9];   // [g=ss*8+tt][h], raw scores then log-probs
    int b = blockIdx.y;
    int s0 = blockIdx.x * 8;
    int tid = threadIdx.x;

    // stage q once
    for (int i = tid; i < 512; i += 256) {
        int row = i >> 6, L = i & 63;
        const bf16* gp = q + ((size_t)(b * 512 + s0 + row)) * 512;
        float4 f0 = ld4bf(gp + 4 * L);
        float4 f1 = ld4bf(gp + 256 + 4 * L);
        *(float4*)&qs[row * 520 + 4 * L] = f0;
        *(float4*)&qs[row * 520 + 256 + 4 * L] = f1;
    }

    // score mapping: wave id = hh
    int hh = tid >> 6;
    int tt = (tid >> 3) & 7;
    int ss = tid & 7;
    int g = ss * 8 + tt;
    // ctx mapping
    int cs = tid >> 5;
    int nb = tid & 31;

    float ctx[16];
    #pragma unroll
    for (int j = 0; j < 16; ++j) ctx[j] = 0.f;

    for (int tc = 0; tc < 512; tc += 8) {
        __syncthreads();
        for (int i = tid; i < 512; i += 256) {
            int row = i >> 6, L = i & 63;
            size_t gb = ((size_t)(b * 512 + tc + row)) * 512;
            float4 k0 = ld4bf(k + gb + 4 * L);
            float4 k1 = ld4bf(k + gb + 256 + 4 * L);
            float4 v0 = ld4bf(v + gb + 4 * L);
            float4 v1 = ld4bf(v + gb + 256 + 4 * L);
            *(float4*)&ks[row * 520 + 4 * L] = k0;
            *(float4*)&ks[row * 520 + 256 + 4 * L] = k1;
            *(float4*)&vs[row * 520 + 4 * L] = v0;
            *(float4*)&vs[row * 520 + 256 + 4 * L] = v1;
        }
        __syncthreads();

        // phase A: raw scores for heads hh, hh+4
        #pragma unroll
        for (int u = 0; u < 2; ++u) {
            int h = hh + 4 * u;
            const float4* qp = (const float4*)&qs[ss * 520 + h * 64];
            const float4* kp = (const float4*)&ks[tt * 520 + h * 64];
            float a = 0.f;
            #pragma unroll
            for (int d4 = 0; d4 < 16; ++d4) {
                float4 qv = qp[d4], kv = kp[d4];
                a += qv.x * kv.x + qv.y * kv.y + qv.z * kv.z + qv.w * kv.w;
            }
            la[g * 9 + h] = a * 0.125f;
        }
        __syncthreads();

        // phase B: log_softmax over the 8 heads (threads 0..63, one per g)
        if (tid < 64) {
            float s[8];
            float m = -1e30f;
            #pragma unroll
            for (int h = 0; h < 8; ++h) { s[h] = la[tid * 9 + h]; m = fmaxf(m, s[h]); }
            float sum = 0.f;
            #pragma unroll
            for (int h = 0; h < 8; ++h) sum += expf(s[h] - m);
            float lse = m + logf(sum);
            #pragma unroll
            for (int h = 0; h < 8; ++h) la[tid * 9 + h] = s[h] - lse;
        }
        __syncthreads();

        // ctx accumulate
        #pragma unroll
        for (int t8 = 0; t8 < 8; ++t8) {
            float lav[8];
            #pragma unroll
            for (int h = 0; h < 8; ++h) lav[h] = la[(cs * 8 + t8) * 9 + h];
            #pragma unroll
            for (int j = 0; j < 16; ++j) {
                int n = nb + (j << 5);
                ctx[j] += lav[j >> 1] * vs[t8 * 520 + n];
            }
        }
    }
    size_t base = ((size_t)(b * 512 + s0 + cs)) * 512;
    #pragma unroll
    for (int j = 0; j < 16; ++j) {
        int n = nb + (j << 5);
        float o = __bfloat162float(o1[base + n]);
        r[base + n] = __float2bfloat16(o + ctx[j]);
    }
}

// ---------------------------------------------------------------------------
// LayerNorm(last dim) -> mean over S -> fc.  One block per (b, s) row.
// ---------------------------------------------------------------------------
__device__ __forceinline__ float block_sum(float val, float* red, int tid)
{
    #pragma unroll
    for (int o = 32; o > 0; o >>= 1) val += __shfl_down(val, o);
    __syncthreads();
    if ((tid & 63) == 0) red[tid >> 6] = val;
    __syncthreads();
    return red[0] + red[1] + red[2] + red[3];
}

__global__ __launch_bounds__(256) void ln_pool_fc(
    const bf16* __restrict__ r, const float* __restrict__ g, const float* __restrict__ bt,
    const float* __restrict__ fcw, const float* __restrict__ fcb, float* __restrict__ out)
{
    __shared__ float red[4];
    int b = blockIdx.y, s = blockIdx.x, tid = threadIdx.x;
    const bf16* row = r + ((size_t)(b * 512 + s)) * 512;
    __hip_bfloat162 rv = *(const __hip_bfloat162*)(row + tid * 2);
    float v0 = __bfloat162float(rv.x), v1 = __bfloat162float(rv.y);
    float tot = block_sum(v0 + v1, red, tid);
    float mu = tot * (1.f / 512.f);
    float d0 = v0 - mu, d1 = v1 - mu;
    float sq = block_sum(d0 * d0 + d1 * d1, red, tid);
    float rs = rsqrtf(sq * (1.f / 512.f) + 1e-5f);
    int n0 = tid * 2;
    float term = d0 * rs * g[n0] * fcw[n0] + d1 * rs * g[n0 + 1] * fcw[n0 + 1];
    if (s == 0) term += 512.f * (bt[n0] * fcw[n0] + bt[n0 + 1] * fcw[n0 + 1]);
    float D = block_sum(term, red, tid);
    if (tid == 0) {
        float val = D * (1.f / 512.f);
        if (s == 0) val += fcb[0];
        atomicAdd(out + b, val);
    }
}

// ---------------------------------------------------------------------------
// Workspace layout (< 200 MiB):
//   [0,64M)    xgf bf16          -> later q,k(first half)
//   [64,128M)  xgb bf16          -> later v (+ spare)
//   [128,160M) out0 bf16
//   [160,192M) out1 bf16 (attention in-place)
//   [192,194M) h0 bf16
//   [194,196M) packed W_hh x4 bf16
//   [196,~199.7M) bf16 weights: Wih0 f/b, Wih1 f/b, Wq, Wk, Wv
// ---------------------------------------------------------------------------
extern "C" void kernel_launch(void* const* d_in, const int* in_sizes, int n_in,
                              void* d_out, int out_size, void* d_ws, size_t ws_size,
                              hipStream_t stream)
{
    (void)in_sizes; (void)n_in; (void)ws_size;
    const float* x      = (const float*)d_in[0];
    const float* conv_w = (const float*)d_in[1];
    const float* conv_b = (const float*)d_in[2];
    const float* bn_g   = (const float*)d_in[3];
    const float* bn_b   = (const float*)d_in[4];
    const float* bn_m   = (const float*)d_in[5];
    const float* bn_v   = (const float*)d_in[6];
    const float* W_ih0f = (const float*)d_in[7];
    const float* W_hh0f = (const float*)d_in[8];
    const float* b0f    = (const float*)d_in[9];
    const float* W_ih0b = (const float*)d_in[10];
    const float* W_hh0b = (const float*)d_in[11];
    const float* b0b    = (const float*)d_in[12];
    const float* W_ih1f = (const float*)d_in[13];
    const float* W_hh1f = (const float*)d_in[14];
    const float* b1f    = (const float*)d_in[15];
    const float* W_ih1b = (const float*)d_in[16];
    const float* W_hh1b = (const float*)d_in[17];
    const float* b1b    = (const float*)d_in[18];
    const float* Wq = (const float*)d_in[19];
    const float* bq = (const float*)d_in[20];
    const float* Wk = (const float*)d_in[21];
    const float* bk = (const float*)d_in[22];
    const float* Wv = (const float*)d_in[23];
    const float* bv = (const float*)d_in[24];
    const float* ln_g = (const float*)d_in[25];
    const float* ln_b = (const float*)d_in[26];
    const float* fc_w = (const float*)d_in[27];
    const float* fc_b = (const float*)d_in[28];
    float* out = (float*)d_out;

    char* ws = (char*)d_ws;
    bf16* xgf  = (bf16*)ws;                               // 33,554,432
    bf16* xgb  = xgf + 33554432;                          // 33,554,432
    bf16* out0 = (bf16*)(ws + 134217728);                 // 16,777,216
    bf16* out1 = (bf16*)(ws + 167772160);                 // 16,777,216
    bf16* h0   = (bf16*)(ws + 201326592);                 // 1,048,576
    bf16* wp0f = (bf16*)(ws + 203423744);                 // 262,144 each
    bf16* wp0b = wp0f + 262144;
    bf16* wp1f = wp0b + 262144;
    bf16* wp1b = wp1f + 262144;
    bf16* wbih0f = wp1b + 262144;                         // 32,768
    bf16* wbih0b = wbih0f + 32768;                        // 32,768
    bf16* wbih1f = wbih0b + 32768;                        // 524,288
    bf16* wbih1b = wbih1f + 524288;                       // 524,288
    bf16* wbq    = wbih1b + 524288;                       // 262,144
    bf16* wbk    = wbq + 262144;                          // 262,144
    bf16* wbv    = wbk + 262144;                          // 262,144
    // q,k,v alias the (dead after lstm1) xg region
    bf16* qb = xgf;
    bf16* kb = xgf + 16777216;
    bf16* vb = xgb;

    hipMemsetAsync(d_out, 0, (size_t)out_size * sizeof(float), stream);

    pack_whh<<<1024, 256, 0, stream>>>(W_hh0f, wp0f);
    pack_whh<<<1024, 256, 0, stream>>>(W_hh0b, wp0b);
    pack_whh<<<1024, 256, 0, stream>>>(W_hh1f, wp1f);
    pack_whh<<<1024, 256, 0, stream>>>(W_hh1b, wp1b);
    pack_bf16<<<128, 256, 0, stream>>>(W_ih0f, wbih0f, 32768);
    pack_bf16<<<128, 256, 0, stream>>>(W_ih0b, wbih0b, 32768);
    pack_bf16<<<2048, 256, 0, stream>>>(W_ih1f, wbih1f, 524288);
    pack_bf16<<<2048, 256, 0, stream>>>(W_ih1b, wbih1b, 524288);
    pack_bf16<<<1024, 256, 0, stream>>>(Wq, wbq, 262144);
    pack_bf16<<<1024, 256, 0, stream>>>(Wk, wbk, 262144);
    pack_bf16<<<1024, 256, 0, stream>>>(Wv, wbv, 262144);

    conv_bn_pool<<<dim3(64, 64), 256, 0, stream>>>(
        x, conv_w, conv_b, bn_g, bn_b, bn_m, bn_v, h0);

    // layer-0 input projections (K=32), fwd+bwd in one launch
    gemm_mfma<<<dim3(8, 256, 2), 256, 0, stream>>>(
        h0, wbih0f, wbih0b, nullptr, b0f, b0b, nullptr, xgf, xgb, nullptr,
        32768, 1024, 32);

    lstm_dual<<<128, 1024, 0, stream>>>(xgf, xgb, wp0f, wp0b, out0);

    // layer-1 input projections (K=512)
    gemm_mfma<<<dim3(8, 256, 2), 256, 0, stream>>>(
        out0, wbih1f, wbih1b, nullptr, b1f, b1b, nullptr, xgf, xgb, nullptr,
        32768, 1024, 512);

    lstm_dual<<<128, 1024, 0, stream>>>(xgf, xgb, wp1f, wp1b, out1);

    // QKV projections (N=512), 3-way
    gemm_mfma<<<dim3(4, 256, 3), 256, 0, stream>>>(
        out1, wbq, wbk, wbv, bq, bk, bv, qb, kb, vb,
        32768, 512, 512);

    attention<<<dim3(64, 64), 256, 0, stream>>>(qb, kb, vb, out1, out1);

    ln_pool_fc<<<dim3(512, 64), 256, 0, stream>>>(out1, ln_g, ln_b, fc_w, fc_b, out);
}